// Round 1
// baseline (25189.958 us; speedup 1.0000x reference)
//
#include <hip/hip_runtime.h>
#include <hip/hip_bf16.h>
#include <math.h>

// Problem constants
constexpr int B_  = 2;
constexpr int T_  = 2048;
constexpr int D_  = 512;     // model dim == IN_DIM == OUT_DIM
constexpr int NH_ = 8;
constexpr int NL_ = 256;     // per-head latent dim N
constexpr int HN_ = NH_ * NL_;  // 2048
constexpr int BT_ = B_ * T_;    // 4096

// ---------------------------------------------------------------------------
// RoPE tables: pc/ps [T][NL].  freq(n) = 2^(-q/16) / (2*pi), q = n & ~1.
// phase = t * f ; p = (phase mod 1) * 2*pi
__global__ __launch_bounds__(256) void rope_tables(float* __restrict__ pc,
                                                   float* __restrict__ ps) {
    int i = blockIdx.x * 256 + threadIdx.x;   // T_*NL_ total
    int t = i / NL_, n = i % NL_;
    int q = n & ~1;
    float f = exp2f(-(float)q * (1.0f / 16.0f)) * (float)(1.0 / (2.0 * M_PI));
    float ph = (float)t * f;
    ph = (ph - floorf(ph)) * (float)(2.0 * M_PI);
    float s, c;
    __sincosf(ph, &s, &c);
    pc[i] = c;
    ps[i] = s;
}

// ---------------------------------------------------------------------------
// Block reduction of two values across 256 threads (wave64 shuffle + LDS)
__device__ inline float2 block_reduce2(float a, float b) {
    __shared__ float sa[4], sb[4];
    #pragma unroll
    for (int off = 32; off; off >>= 1) {
        a += __shfl_down(a, off, 64);
        b += __shfl_down(b, off, 64);
    }
    __syncthreads();   // protect sa/sb reuse across calls
    int w = threadIdx.x >> 6;
    if ((threadIdx.x & 63) == 0) { sa[w] = a; sb[w] = b; }
    __syncthreads();
    return make_float2(sa[0] + sa[1] + sa[2] + sa[3],
                       sb[0] + sb[1] + sb[2] + sb[3]);
}

// LayerNorm of a 512-wide row held as one float2 per thread (2-pass, centered
// variance to match jnp.var numerics).
__device__ inline float2 ln_pair(float2 v) {
    float2 s = block_reduce2(v.x + v.y, 0.f);
    float mu = s.x * (1.0f / 512.0f);
    float dx = v.x - mu, dy = v.y - mu;
    float2 q = block_reduce2(dx * dx + dy * dy, 0.f);
    float inv = rsqrtf(q.x * (1.0f / 512.0f) + 1e-5f);
    return make_float2(dx * inv, dy * inv);
}

// out = LN(in) over rows of 512; safe in-place (each thread reads only its own
// two elements before any write).
__global__ __launch_bounds__(256) void ln_rows(const float* __restrict__ in,
                                               float* __restrict__ out) {
    long row = blockIdx.x;
    float2 v = *(const float2*)&in[row * 512 + threadIdx.x * 2];
    float2 o = ln_pair(v);
    *(float2*)&out[row * 512 + threadIdx.x * 2] = o;
}

// xs_next = LN(x_res + LN(ymlp)) per row of 512
__global__ __launch_bounds__(256) void combine_k(const float* __restrict__ ymlp,
                                                 const float* __restrict__ xres,
                                                 float* __restrict__ xout) {
    long row = blockIdx.x;
    float2 y = *(const float2*)&ymlp[row * 512 + threadIdx.x * 2];
    float2 l = ln_pair(y);
    float2 r = *(const float2*)&xres[row * 512 + threadIdx.x * 2];
    float2 z = make_float2(r.x + l.x, r.y + l.y);
    float2 o = ln_pair(z);
    *(float2*)&xout[row * 512 + threadIdx.x * 2] = o;
}

// ---------------------------------------------------------------------------
// RoPE: qr = rope(xsp).  Layout [BT][HN], head h occupies cols h*NL..h*NL+255.
// Pair (2i, 2i+1): out0 = v0*c - v1*s ; out1 = v1*c + v0*s, angle from n=2i.
__global__ __launch_bounds__(256) void rope_k(const float* __restrict__ xsp,
                                              const float* __restrict__ pc,
                                              const float* __restrict__ ps,
                                              float* __restrict__ qr) {
    long i = (long)blockIdx.x * 256 + threadIdx.x;  // pair index, BT*HN/2 total
    long col2 = i % (HN_ / 2);
    long row  = i / (HN_ / 2);
    int n2 = (int)(col2 % (NL_ / 2));  // pair index within head
    int t  = (int)(row % T_);          // row = b*T + t
    float c = pc[t * NL_ + n2 * 2];
    float s = ps[t * NL_ + n2 * 2];
    float2 v = *(const float2*)&xsp[row * HN_ + col2 * 2];
    float2 o = make_float2(v.x * c - v.y * s, v.y * c + v.x * s);
    *(float2*)&qr[row * HN_ + col2 * 2] = o;
}

// ---------------------------------------------------------------------------
// Generic fp32 tiled GEMM: C[M,N] = A[M,K] @ B[K,N] (+bias) (relu) (*mul)
// 64x64 tile, BK=16, 256 threads, 4x4 micro-tile. blockIdx.z batches with
// element strides.  mul uses identical indexing to C.
template <bool BIAS, bool RELU, bool MUL>
__global__ __launch_bounds__(256) void gemm_f32(
    const float* __restrict__ A, int lda, long strideA,
    const float* __restrict__ Bm, int ldb, long strideB,
    float* __restrict__ C, int ldc, long strideC,
    const float* __restrict__ bias, const float* __restrict__ mul,
    int M, int N, int K) {
    __shared__ float As[16][65];  // As[k][m]
    __shared__ float Bs[16][65];  // Bs[k][n]
    int z = blockIdx.z;
    A  += (long)z * strideA;
    Bm += (long)z * strideB;
    C  += (long)z * strideC;
    const float* mulp = MUL ? (mul + (long)z * strideC) : nullptr;
    int tile_n = blockIdx.x * 64;
    int tile_m = blockIdx.y * 64;
    int tid = threadIdx.x;
    int tx = tid & 15, ty = tid >> 4;
    float acc[4][4] = {};
    int ar  = tid >> 2;        // A load: row 0..63
    int akc = (tid & 3) * 4;   // A load: 4 k's
    int bk  = tid >> 4;        // B load: k 0..15
    int bnc = (tid & 15) * 4;  // B load: 4 n's
    for (int k0 = 0; k0 < K; k0 += 16) {
        float4 av = *(const float4*)&A[(long)(tile_m + ar) * lda + k0 + akc];
        As[akc + 0][ar] = av.x;
        As[akc + 1][ar] = av.y;
        As[akc + 2][ar] = av.z;
        As[akc + 3][ar] = av.w;
        float4 bv = *(const float4*)&Bm[(long)(k0 + bk) * ldb + tile_n + bnc];
        Bs[bk][bnc + 0] = bv.x;
        Bs[bk][bnc + 1] = bv.y;
        Bs[bk][bnc + 2] = bv.z;
        Bs[bk][bnc + 3] = bv.w;
        __syncthreads();
        #pragma unroll
        for (int kk = 0; kk < 16; ++kk) {
            float a0 = As[kk][ty * 4 + 0], a1 = As[kk][ty * 4 + 1];
            float a2 = As[kk][ty * 4 + 2], a3 = As[kk][ty * 4 + 3];
            float b0 = Bs[kk][tx * 4 + 0], b1 = Bs[kk][tx * 4 + 1];
            float b2 = Bs[kk][tx * 4 + 2], b3 = Bs[kk][tx * 4 + 3];
            acc[0][0] += a0 * b0; acc[0][1] += a0 * b1; acc[0][2] += a0 * b2; acc[0][3] += a0 * b3;
            acc[1][0] += a1 * b0; acc[1][1] += a1 * b1; acc[1][2] += a1 * b2; acc[1][3] += a1 * b3;
            acc[2][0] += a2 * b0; acc[2][1] += a2 * b1; acc[2][2] += a2 * b2; acc[2][3] += a2 * b3;
            acc[3][0] += a3 * b0; acc[3][1] += a3 * b1; acc[3][2] += a3 * b2; acc[3][3] += a3 * b3;
        }
        __syncthreads();
    }
    #pragma unroll
    for (int i = 0; i < 4; ++i) {
        int row = tile_m + ty * 4 + i;
        #pragma unroll
        for (int j = 0; j < 4; ++j) {
            int col = tile_n + tx * 4 + j;
            float v = acc[i][j];
            if (BIAS) v += bias[col];
            if (RELU) v = fmaxf(v, 0.f);
            long idx = (long)row * ldc + col;
            if (MUL) v *= mulp[idx];
            C[idx] = v;
        }
    }
}

// ---------------------------------------------------------------------------
// Fused attention: for each (b, h, t-tile of 32):
//   S = (QR_t . QR_s^T) with STRICT causal mask (t > s, diag excluded),
//   yKV_t += S @ xs_s        accumulated over all needed s-tiles.
// QR layout [BT][HN]; xs [BT][D]; ykv [NH][BT][D].
__global__ __launch_bounds__(256) void attn_f32(const float* __restrict__ qr,
                                                const float* __restrict__ xs,
                                                float* __restrict__ ykv) {
    __shared__ float qs[32][NL_];   // 32 KB: Q tile
    __shared__ float ss[32][33];    // masked score tile
    int tid = threadIdx.x;
    int tt = blockIdx.x, h = blockIdx.y, b = blockIdx.z;
    int t0 = tt * 32;   // within batch
    long qbase = ((long)(b * T_ + t0)) * HN_ + h * NL_;
    // stage Q tile
    for (int i = tid; i < 32 * NL_ / 4; i += 256) {
        int r  = i >> 6;            // NL_/4 == 64
        int c4 = (i & 63) << 2;
        *(float4*)&qs[r][c4] = *(const float4*)&qr[qbase + (long)r * HN_ + c4];
    }
    __syncthreads();
    // yKV accumulator: thread owns rows rg*4..+3, cols c0..c0+15
    int rg = tid >> 5;
    int c0 = (tid & 31) * 16;
    float4 acc[4][4] = {};
    // Phase A mapping: thread computes S[sr][sc0..sc0+3]
    int sr  = tid >> 3;
    int sc0 = (tid & 7) * 4;
    for (int st = 0; st <= tt; ++st) {
        int s0 = st * 32;
        // ---- Phase A: scores ----
        const float* k0 = &qr[((long)(b * T_ + s0 + sc0 + 0)) * HN_ + h * NL_];
        const float* k1 = k0 + HN_;
        const float* k2 = k1 + HN_;
        const float* k3 = k2 + HN_;
        float4 sv = make_float4(0.f, 0.f, 0.f, 0.f);
        for (int n4 = 0; n4 < NL_; n4 += 4) {
            float4 q  = *(const float4*)&qs[sr][n4];
            float4 a0 = *(const float4*)&k0[n4];
            float4 a1 = *(const float4*)&k1[n4];
            float4 a2 = *(const float4*)&k2[n4];
            float4 a3 = *(const float4*)&k3[n4];
            sv.x += q.x * a0.x + q.y * a0.y + q.z * a0.z + q.w * a0.w;
            sv.y += q.x * a1.x + q.y * a1.y + q.z * a1.z + q.w * a1.w;
            sv.z += q.x * a2.x + q.y * a2.y + q.z * a2.z + q.w * a2.w;
            sv.w += q.x * a3.x + q.y * a3.y + q.z * a3.z + q.w * a3.w;
        }
        int tg = t0 + sr;
        ss[sr][sc0 + 0] = (tg > s0 + sc0 + 0) ? sv.x : 0.f;
        ss[sr][sc0 + 1] = (tg > s0 + sc0 + 1) ? sv.y : 0.f;
        ss[sr][sc0 + 2] = (tg > s0 + sc0 + 2) ? sv.z : 0.f;
        ss[sr][sc0 + 3] = (tg > s0 + sc0 + 3) ? sv.w : 0.f;
        __syncthreads();
        // ---- Phase B: yKV += S @ xs ----
        for (int s = 0; s < 32; ++s) {
            const float4* xrow =
                (const float4*)&xs[((long)(b * T_ + s0 + s)) * D_ + c0];
            float4 x0 = xrow[0], x1 = xrow[1], x2 = xrow[2], x3 = xrow[3];
            #pragma unroll
            for (int i = 0; i < 4; ++i) {
                float w = ss[rg * 4 + i][s];
                acc[i][0].x += w * x0.x; acc[i][0].y += w * x0.y;
                acc[i][0].z += w * x0.z; acc[i][0].w += w * x0.w;
                acc[i][1].x += w * x1.x; acc[i][1].y += w * x1.y;
                acc[i][1].z += w * x1.z; acc[i][1].w += w * x1.w;
                acc[i][2].x += w * x2.x; acc[i][2].y += w * x2.y;
                acc[i][2].z += w * x2.z; acc[i][2].w += w * x2.w;
                acc[i][3].x += w * x3.x; acc[i][3].y += w * x3.y;
                acc[i][3].z += w * x3.z; acc[i][3].w += w * x3.w;
            }
        }
        __syncthreads();
    }
    #pragma unroll
    for (int i = 0; i < 4; ++i) {
        long row = (long)h * BT_ + (long)b * T_ + t0 + rg * 4 + i;
        #pragma unroll
        for (int j = 0; j < 4; ++j) {
            *(float4*)&ykv[row * D_ + c0 + j * 4] = acc[i][j];
        }
    }
}

// ---------------------------------------------------------------------------
extern "C" void kernel_launch(void* const* d_in, const int* in_sizes, int n_in,
                              void* d_out, int out_size, void* d_ws,
                              size_t ws_size, hipStream_t stream) {
    const float* x      = (const float*)d_in[0];
    const float* w_in   = (const float*)d_in[1];
    const float* b_in   = (const float*)d_in[2];
    const float* enc    = (const float*)d_in[3];
    const float* enc_v  = (const float*)d_in[4];
    const float* dec    = (const float*)d_in[5];
    const float* head_w = (const float*)d_in[6];
    const float* head_b = (const float*)d_in[7];
    float* out = (float*)d_out;

    // Workspace layout (floats): ~197 MB total
    float* p   = (float*)d_ws;
    float* pc  = p; p += (long)T_ * NL_;
    float* ps  = p; p += (long)T_ * NL_;
    float* xsa = p; p += (long)BT_ * D_;
    float* xsb = p; p += (long)BT_ * D_;
    float* xsp = p; p += (long)BT_ * HN_;   // x_sparse  [BT][HN]
    float* qrb = p; p += (long)BT_ * HN_;   // QR        [BT][HN]
    float* xy  = p; p += (long)BT_ * HN_;   // x_sparse*y_sparse [BT][HN]
    float* ymlp= p; p += (long)BT_ * D_;
    float* ykv = p; p += (long)NH_ * BT_ * D_;  // [NH][BT][D]

    rope_tables<<<T_ * NL_ / 256, 256, 0, stream>>>(pc, ps);

    // xs = LN(x @ w_in + b_in)
    gemm_f32<true, false, false><<<dim3(D_ / 64, BT_ / 64, 1), 256, 0, stream>>>(
        x, D_, 0, w_in, D_, 0, xsa, D_, 0, b_in, nullptr, BT_, D_, D_);
    ln_rows<<<BT_, 256, 0, stream>>>(xsa, xsa);

    float* xin = xsa;
    float* xnext = xsb;
    for (int l = 0; l < 3; ++l) {
        // x_sparse = relu(xs @ encoder[h]) -> [BT][h*NL + n]
        gemm_f32<false, true, false>
            <<<dim3(NL_ / 64, BT_ / 64, NH_), 256, 0, stream>>>(
                xin, D_, 0, enc, NL_, (long)D_ * NL_, xsp, HN_, NL_, nullptr,
                nullptr, BT_, NL_, D_);
        // QR = rope(x_sparse)
        rope_k<<<(long)BT_ * HN_ / 2 / 256, 256, 0, stream>>>(xsp, pc, ps, qrb);
        // yKV = (mask o (QR QR^T)) @ xs
        attn_f32<<<dim3(T_ / 32, NH_, B_), 256, 0, stream>>>(qrb, xin, ykv);
        // yKV = LN(yKV)
        ln_rows<<<NH_ * BT_, 256, 0, stream>>>(ykv, ykv);
        // xy = relu(yKV @ encoder_v[h]) * x_sparse
        gemm_f32<false, true, true>
            <<<dim3(NL_ / 64, BT_ / 64, NH_), 256, 0, stream>>>(
                ykv, D_, (long)BT_ * D_, enc_v, NL_, (long)D_ * NL_, xy, HN_,
                NL_, nullptr, xsp, BT_, NL_, D_);
        // yMLP = xy @ decoder   ([BT,HN] @ [HN,D])
        gemm_f32<false, false, false>
            <<<dim3(D_ / 64, BT_ / 64, 1), 256, 0, stream>>>(
                xy, HN_, 0, dec, D_, 0, ymlp, D_, 0, nullptr, nullptr, BT_, D_,
                HN_);
        // xs = LN(x_res + LN(yMLP))
        combine_k<<<BT_, 256, 0, stream>>>(ymlp, xin, xnext);
        float* t = xin; xin = xnext; xnext = t;
    }

    // logits = xs @ head_w + head_b
    gemm_f32<true, false, false><<<dim3(D_ / 64, BT_ / 64, 1), 256, 0, stream>>>(
        xin, D_, 0, head_w, D_, 0, out, D_, 0, head_b, nullptr, BT_, D_, D_);
}

// Round 2
// 1079.978 us; speedup vs baseline: 23.3245x; 23.3245x over previous
//
#include <hip/hip_runtime.h>
#include <math.h>

constexpr int B_  = 2;
constexpr int T_  = 2048;
constexpr int D_  = 512;
constexpr int NH_ = 8;
constexpr int NL_ = 256;
constexpr int HN_ = NH_ * NL_;   // 2048
constexpr int BT_ = B_ * T_;     // 4096

typedef __bf16 v8bf __attribute__((ext_vector_type(8)));
typedef float  v4f  __attribute__((ext_vector_type(4)));
typedef unsigned short us8 __attribute__((ext_vector_type(8)));

__device__ inline unsigned short f2b(float f) {
    union { float f; unsigned u; } v{f};
    unsigned r = v.u + 0x7FFF + ((v.u >> 16) & 1);   // rtne
    return (unsigned short)(r >> 16);
}
__device__ inline float b2f(unsigned short u) {
    union { unsigned u; float f; } v{(unsigned)u << 16};
    return v.f;
}

// ---------------------------------------------------------------------------
// bf16 MFMA GEMM: C[M,N] = A[M,K] @ Bt[N,K]^T   (Bt is K-major, i.e. B^T)
// 128x128 tile, BK=32, 256 threads = 4 waves (2x2 of 64x64), 4x4 MFMAs/wave.
// Batched via blockIdx.z: off = z * s{A,B,C} elements.
// MASK: strict-causal (keep iff row>col), skip tiles fully above diagonal.
// KLIM: K-loop bounded at m0+128 (causal P@X).
// MUL:  multiply by bf16 operand at C's index. BF16OUT: emit bf16 else fp32.
template <bool BIAS, bool RELU, bool MUL, bool MASK, bool KLIM, bool BF16OUT>
__global__ __launch_bounds__(256) void gemm_bf16(
    const unsigned short* __restrict__ A, int lda, long sA,
    const unsigned short* __restrict__ Bt, int ldb, long sB,
    void* __restrict__ Cv, int ldc, long sC,
    const float* __restrict__ bias, const unsigned short* __restrict__ mulp,
    int M, int N, int K) {
    int m0 = blockIdx.y * 128, n0 = blockIdx.x * 128, z = blockIdx.z;
    if (MASK && n0 > m0) return;   // tile entirely above diagonal: never read
    __shared__ unsigned short As[128][40];   // +8 bf16 pad: 2-way alias only
    __shared__ unsigned short Bs[128][40];
    const unsigned short* Ab = A  + (long)z * sA + (long)m0 * lda;
    const unsigned short* Bb = Bt + (long)z * sB + (long)n0 * ldb;
    int tid  = threadIdx.x;
    int lane = tid & 63, wid = tid >> 6;
    int wm = (wid & 1) * 64, wn = (wid >> 1) * 64;
    int ln16 = lane & 15, q = lane >> 4;
    int srow = tid >> 2, sseg = (tid & 3) * 8;
    v4f acc[4][4] = {};
    int kend = KLIM ? (K < m0 + 128 ? K : m0 + 128) : K;
    for (int k0 = 0; k0 < kend; k0 += 32) {
        #pragma unroll
        for (int i = 0; i < 2; ++i) {
            int r = srow + i * 64;
            *(us8*)&As[r][sseg] = *(const us8*)&Ab[(long)r * lda + k0 + sseg];
            *(us8*)&Bs[r][sseg] = *(const us8*)&Bb[(long)r * ldb + k0 + sseg];
        }
        __syncthreads();
        v8bf af[4], bfr[4];
        #pragma unroll
        for (int r = 0; r < 4; ++r)
            af[r] = *(const v8bf*)&As[wm + r * 16 + ln16][q * 8];
        #pragma unroll
        for (int c = 0; c < 4; ++c)
            bfr[c] = *(const v8bf*)&Bs[wn + c * 16 + ln16][q * 8];
        #pragma unroll
        for (int r = 0; r < 4; ++r)
            #pragma unroll
            for (int c = 0; c < 4; ++c)
                acc[r][c] = __builtin_amdgcn_mfma_f32_16x16x32_bf16(
                    af[r], bfr[c], acc[r][c], 0, 0, 0);
        __syncthreads();
    }
    float* Cf = (float*)Cv;
    unsigned short* Cb = (unsigned short*)Cv;
    long zoff = (long)z * sC;
    #pragma unroll
    for (int r = 0; r < 4; ++r) {
        #pragma unroll
        for (int c = 0; c < 4; ++c) {
            #pragma unroll
            for (int e = 0; e < 4; ++e) {
                int row = m0 + wm + r * 16 + q * 4 + e;
                int col = n0 + wn + c * 16 + ln16;
                float v = acc[r][c][e];
                if (BIAS) v += bias[col];
                if (RELU) v = fmaxf(v, 0.f);
                if (MASK && row <= col) v = 0.f;
                long idx = zoff + (long)row * ldc + col;
                if (MUL) v *= b2f(mulp[idx]);
                if (BF16OUT) Cb[idx] = f2b(v);
                else         Cf[idx] = v;
            }
        }
    }
}

// ---------------------------------------------------------------------------
// Transpose + cast fp32 -> bf16: out[Cc][R] = (bf16) in[R][Cc], batched.
__global__ __launch_bounds__(256) void trans_cast(
    const float* __restrict__ in, long sIn, unsigned short* __restrict__ out,
    long sOut, int R, int Cc) {
    __shared__ float tl[32][33];
    int z = blockIdx.z;
    int r0 = blockIdx.y * 32, c0 = blockIdx.x * 32;
    int tx = threadIdx.x & 31, ty = threadIdx.x >> 5;
    const float* ip = in + (long)z * sIn;
    unsigned short* op = out + (long)z * sOut;
    #pragma unroll
    for (int j = 0; j < 4; ++j)
        tl[ty + j * 8][tx] = ip[(long)(r0 + ty + j * 8) * Cc + c0 + tx];
    __syncthreads();
    #pragma unroll
    for (int j = 0; j < 4; ++j)
        op[(long)(c0 + ty + j * 8) * R + r0 + tx] = f2b(tl[tx][ty + j * 8]);
}

// fp32 -> bf16 elementwise (n multiple of 1024)
__global__ __launch_bounds__(256) void cast_b(const float* __restrict__ in,
                                              unsigned short* __restrict__ out) {
    long i = ((long)blockIdx.x * 256 + threadIdx.x) * 4;
    float4 v = *(const float4*)&in[i];
    ushort4 o;
    o.x = f2b(v.x); o.y = f2b(v.y); o.z = f2b(v.z); o.w = f2b(v.w);
    *(ushort4*)&out[i] = o;
}

// ---------------------------------------------------------------------------
// RoPE on bf16 [BT][HN]; angle computed inline (THETA=2^16, N=256:
// freq = 2^(-q/16)/(2*pi), q = 2*pair_index_in_head).
__global__ __launch_bounds__(256) void rope_b(const unsigned short* __restrict__ xsp,
                                              unsigned short* __restrict__ qr) {
    long i = (long)blockIdx.x * 256 + threadIdx.x;   // pair id, BT*HN/2 total
    int col2 = (int)(i & (HN_ / 2 - 1));
    long row = i >> 10;                              // HN/2 = 1024
    int n2 = col2 & (NL_ / 2 - 1);
    int t  = (int)(row & (T_ - 1));
    float f = exp2f(-(float)n2 * 0.125f) * (float)(1.0 / (2.0 * M_PI));
    float ph = (float)t * f;
    ph = (ph - floorf(ph)) * (float)(2.0 * M_PI);
    float s, c;
    __sincosf(ph, &s, &c);
    ushort2 u = *(const ushort2*)&xsp[row * HN_ + col2 * 2];
    float x0 = b2f(u.x), x1 = b2f(u.y);
    ushort2 o;
    o.x = f2b(x0 * c - x1 * s);
    o.y = f2b(x1 * c + x0 * s);
    *(ushort2*)&qr[row * HN_ + col2 * 2] = o;
}

// ---------------------------------------------------------------------------
// LayerNorm helpers (rows of 512, 256 threads, float2 per thread)
__device__ inline float2 block_reduce2(float a, float b) {
    __shared__ float sa[4], sb[4];
    #pragma unroll
    for (int off = 32; off; off >>= 1) {
        a += __shfl_down(a, off, 64);
        b += __shfl_down(b, off, 64);
    }
    __syncthreads();
    int w = threadIdx.x >> 6;
    if ((threadIdx.x & 63) == 0) { sa[w] = a; sb[w] = b; }
    __syncthreads();
    return make_float2(sa[0] + sa[1] + sa[2] + sa[3],
                       sb[0] + sb[1] + sb[2] + sb[3]);
}
__device__ inline float2 ln_pair(float2 v) {
    float2 s = block_reduce2(v.x + v.y, 0.f);
    float mu = s.x * (1.0f / 512.0f);
    float dx = v.x - mu, dy = v.y - mu;
    float2 q = block_reduce2(dx * dx + dy * dy, 0.f);
    float inv = rsqrtf(q.x * (1.0f / 512.0f) + 1e-5f);
    return make_float2(dx * inv, dy * inv);
}

// LN fp32 in -> fp32 + bf16 out
__global__ __launch_bounds__(256) void ln_dual(const float* __restrict__ in,
                                               float* __restrict__ outf,
                                               unsigned short* __restrict__ outb) {
    long row = blockIdx.x;
    float2 v = *(const float2*)&in[row * 512 + threadIdx.x * 2];
    float2 o = ln_pair(v);
    *(float2*)&outf[row * 512 + threadIdx.x * 2] = o;
    ushort2 ob; ob.x = f2b(o.x); ob.y = f2b(o.y);
    *(ushort2*)&outb[row * 512 + threadIdx.x * 2] = ob;
}

// LN bf16 in-place
__global__ __launch_bounds__(256) void ln_b16(unsigned short* __restrict__ buf) {
    long row = blockIdx.x;
    ushort2 u = *(const ushort2*)&buf[row * 512 + threadIdx.x * 2];
    float2 v = make_float2(b2f(u.x), b2f(u.y));
    float2 o = ln_pair(v);
    ushort2 ob; ob.x = f2b(o.x); ob.y = f2b(o.y);
    *(ushort2*)&buf[row * 512 + threadIdx.x * 2] = ob;
}

// xs_next = LN(x_res + LN(ymlp)) -> fp32 + bf16
__global__ __launch_bounds__(256) void combine_dual(
    const float* __restrict__ ymlp, const float* __restrict__ xres,
    float* __restrict__ outf, unsigned short* __restrict__ outb) {
    long row = blockIdx.x;
    float2 y = *(const float2*)&ymlp[row * 512 + threadIdx.x * 2];
    float2 l = ln_pair(y);
    float2 r = *(const float2*)&xres[row * 512 + threadIdx.x * 2];
    float2 z = make_float2(r.x + l.x, r.y + l.y);
    float2 o = ln_pair(z);
    *(float2*)&outf[row * 512 + threadIdx.x * 2] = o;
    ushort2 ob; ob.x = f2b(o.x); ob.y = f2b(o.y);
    *(ushort2*)&outb[row * 512 + threadIdx.x * 2] = ob;
}

// ---------------------------------------------------------------------------
extern "C" void kernel_launch(void* const* d_in, const int* in_sizes, int n_in,
                              void* d_out, int out_size, void* d_ws,
                              size_t ws_size, hipStream_t stream) {
    const float* x      = (const float*)d_in[0];
    const float* w_in   = (const float*)d_in[1];
    const float* b_in   = (const float*)d_in[2];
    const float* enc    = (const float*)d_in[3];
    const float* enc_v  = (const float*)d_in[4];
    const float* dec    = (const float*)d_in[5];
    const float* head_w = (const float*)d_in[6];
    const float* head_b = (const float*)d_in[7];
    float* out = (float*)d_out;

    // ---- workspace layout (~174 MB) ----
    char* w = (char*)d_ws;
    auto alloc = [&](size_t bytes) { void* p = (void*)w; w += bytes; return p; };
    unsigned short* w_inT = (unsigned short*)alloc((size_t)512 * 512 * 2);
    unsigned short* headT = (unsigned short*)alloc((size_t)512 * 512 * 2);
    unsigned short* encT  = (unsigned short*)alloc((size_t)NH_ * NL_ * D_ * 2);
    unsigned short* encvT = (unsigned short*)alloc((size_t)NH_ * NL_ * D_ * 2);
    unsigned short* decT  = (unsigned short*)alloc((size_t)D_ * HN_ * 2);
    unsigned short* xb    = (unsigned short*)alloc((size_t)BT_ * D_ * 2);
    float*          tmp   = (float*)alloc((size_t)BT_ * D_ * 4);
    float*          xsf0  = (float*)alloc((size_t)BT_ * D_ * 4);
    float*          xsf1  = (float*)alloc((size_t)BT_ * D_ * 4);
    unsigned short* xs_b  = (unsigned short*)alloc((size_t)BT_ * D_ * 2);
    unsigned short* xsT   = (unsigned short*)alloc((size_t)B_ * D_ * T_ * 2);
    unsigned short* xsp   = (unsigned short*)alloc((size_t)BT_ * HN_ * 2);
    unsigned short* qr    = (unsigned short*)alloc((size_t)BT_ * HN_ * 2);
    unsigned short* Sm    = (unsigned short*)alloc((size_t)NH_ * T_ * T_ * 2);
    unsigned short* ykv   = (unsigned short*)alloc((size_t)NH_ * BT_ * D_ * 2);

    // ---- prep: casts + weight transposes (K-major B operands) ----
    cast_b<<<BT_ * D_ / 1024, 256, 0, stream>>>(x, xb);
    trans_cast<<<dim3(16, 16, 1), 256, 0, stream>>>(w_in, 0, w_inT, 0, 512, 512);
    trans_cast<<<dim3(16, 16, 1), 256, 0, stream>>>(head_w, 0, headT, 0, 512, 512);
    trans_cast<<<dim3(8, 16, 8), 256, 0, stream>>>(enc, (long)D_ * NL_, encT,
                                                   (long)NL_ * D_, D_, NL_);
    trans_cast<<<dim3(8, 16, 8), 256, 0, stream>>>(enc_v, (long)D_ * NL_, encvT,
                                                   (long)NL_ * D_, D_, NL_);
    trans_cast<<<dim3(16, 64, 1), 256, 0, stream>>>(dec, 0, decT, 0, HN_, D_);

    // ---- xs = LN(x @ w_in + b_in) ----
    gemm_bf16<true, false, false, false, false, false>
        <<<dim3(4, 32, 1), 256, 0, stream>>>(xb, D_, 0, w_inT, D_, 0, tmp, D_, 0,
                                             b_in, nullptr, BT_, D_, D_);
    ln_dual<<<BT_, 256, 0, stream>>>(tmp, xsf0, xs_b);
    trans_cast<<<dim3(16, 64, 2), 256, 0, stream>>>(xsf0, (long)T_ * D_, xsT,
                                                    (long)D_ * T_, T_, D_);

    float* xin = xsf0;
    float* xout = xsf1;
    for (int l = 0; l < 3; ++l) {
        // x_sparse = relu(xs @ enc[h])  -> bf16 [BT][HN]
        gemm_bf16<false, true, false, false, false, true>
            <<<dim3(2, 32, 8), 256, 0, stream>>>(
                xs_b, D_, 0, encT, D_, (long)NL_ * D_, xsp, HN_, NL_, nullptr,
                nullptr, BT_, NL_, D_);
        // QR = rope(x_sparse)
        rope_b<<<BT_ * HN_ / 2 / 256, 256, 0, stream>>>(xsp, qr);
        // attention, per batch b (S buffer sized [NH][T][T])
        for (int b = 0; b < B_; ++b) {
            const unsigned short* qrb = qr + (long)b * T_ * HN_;
            // S = strict_tril(QR QR^T)  (upper tiles skipped, never read)
            gemm_bf16<false, false, false, true, false, true>
                <<<dim3(16, 16, 8), 256, 0, stream>>>(
                    qrb, HN_, NL_, qrb, HN_, NL_, Sm, T_, (long)T_ * T_,
                    nullptr, nullptr, T_, T_, NL_);
            // yKV = S @ xs   (K-loop bounded causally) -> bf16 [h][b][T][D]
            gemm_bf16<false, false, false, false, true, true>
                <<<dim3(4, 16, 8), 256, 0, stream>>>(
                    Sm, T_, (long)T_ * T_, xsT + (long)b * D_ * T_, T_, 0,
                    ykv + (long)b * T_ * D_, D_, (long)BT_ * D_, nullptr,
                    nullptr, T_, D_, T_);
        }
        // yKV = LN(yKV), in place (bf16)
        ln_b16<<<NH_ * BT_, 256, 0, stream>>>(ykv);
        // xy = relu(yKV @ enc_v[h]) * x_sparse   (in-place into xsp)
        gemm_bf16<false, true, true, false, false, true>
            <<<dim3(2, 32, 8), 256, 0, stream>>>(
                ykv, D_, (long)BT_ * D_, encvT, D_, (long)NL_ * D_, xsp, HN_,
                NL_, nullptr, xsp, BT_, NL_, D_);
        // yMLP = xy @ decoder -> fp32
        gemm_bf16<false, false, false, false, false, false>
            <<<dim3(4, 32, 1), 256, 0, stream>>>(
                xsp, HN_, 0, decT, HN_, 0, tmp, D_, 0, nullptr, nullptr, BT_,
                D_, HN_);
        // xs = LN(x_res + LN(yMLP))
        combine_dual<<<BT_, 256, 0, stream>>>(tmp, xin, xout, xs_b);
        trans_cast<<<dim3(16, 64, 2), 256, 0, stream>>>(xout, (long)T_ * D_,
                                                        xsT, (long)D_ * T_, T_,
                                                        D_);
        float* t = xin; xin = xout; xout = t;
    }

    // logits = xs @ head_w + head_b
    gemm_bf16<true, false, false, false, false, false>
        <<<dim3(4, 32, 1), 256, 0, stream>>>(xs_b, D_, 0, headT, D_, 0, out, D_,
                                             0, head_b, nullptr, BT_, D_, D_);
}

// Round 3
// 972.826 us; speedup vs baseline: 25.8936x; 1.1101x over previous
//
#include <hip/hip_runtime.h>
#include <math.h>

constexpr int B_  = 2;
constexpr int T_  = 2048;
constexpr int D_  = 512;
constexpr int NH_ = 8;
constexpr int NL_ = 256;
constexpr int HN_ = NH_ * NL_;   // 2048
constexpr int BT_ = B_ * T_;     // 4096

typedef __bf16 v8bf __attribute__((ext_vector_type(8)));
typedef float  v4f  __attribute__((ext_vector_type(4)));
typedef unsigned short us8 __attribute__((ext_vector_type(8)));

__device__ inline unsigned short f2b(float f) {
    union { float f; unsigned u; } v{f};
    unsigned r = v.u + 0x7FFF + ((v.u >> 16) & 1);   // rtne
    return (unsigned short)(r >> 16);
}
__device__ inline float b2f(unsigned short u) {
    union { unsigned u; float f; } v{(unsigned)u << 16};
    return v.f;
}

// async 16B global->LDS (per-lane gaddr; LDS dest = wave-uniform base + lane*16)
__device__ __forceinline__ void g2l16(const void* g, void* l) {
    __builtin_amdgcn_global_load_lds(
        (const __attribute__((address_space(1))) void*)g,
        (__attribute__((address_space(3))) void*)l, 16, 0, 0);
}

// ---------------------------------------------------------------------------
// bf16 MFMA GEMM (m97 structure): C[M,N] = A[M,K] @ Bt[N,K]^T, Bt K-major.
// 128x128 tile, BK=32, 256 thr = 4 waves (2x2 of 64x64), 4x4 MFMA/wave.
// Staging via global_load_lds dwordx4 into unpadded LDS [128][32].
// z batches with element strides (also used for split-K via sA=sB=Khalf).
// MASK: strict-causal (row>col keeps), skips tiles above diagonal.
// KLIM: K-loop bounded at m0+128.  MUL: *bf16 at C idx.  BF16OUT: bf16 else f32.
template <bool RELU, bool MUL, bool MASK, bool KLIM, bool BF16OUT>
__global__ __launch_bounds__(256) void gemm_bf16(
    const unsigned short* __restrict__ A, int lda, long sA,
    const unsigned short* __restrict__ Bt, int ldb, long sB,
    void* __restrict__ Cv, int ldc, long sC,
    const unsigned short* __restrict__ mulp, int M, int N, int K) {
    int m0 = blockIdx.y * 128, n0 = blockIdx.x * 128, z = blockIdx.z;
    if (MASK && n0 > m0) return;
    __shared__ unsigned short As[128][32];   // 8 KB, contiguous (load_lds order)
    __shared__ unsigned short Bs[128][32];
    const unsigned short* Ab = A  + (long)z * sA + (long)m0 * lda;
    const unsigned short* Bb = Bt + (long)z * sB + (long)n0 * ldb;
    int tid = threadIdx.x;
    int lane = tid & 63, wid = tid >> 6;
    int wm = (wid & 1) * 64, wn = (wid >> 1) * 64;
    int ln16 = lane & 15, q = lane >> 4;
    v4f acc[4][4] = {};
    int kend = KLIM ? (K < m0 + 128 ? K : m0 + 128) : K;
    // staging map: issue i covers byte chunk (wid*2+i)*1024 of the 8KB tile;
    // lane's element e = chunk/2 + lane*8 -> row e/32, col e%32.
    int e0 = (wid * 2 + 0) * 512 + lane * 8;
    int e1 = (wid * 2 + 1) * 512 + lane * 8;
    int r0 = e0 >> 5, c0 = e0 & 31, r1 = e1 >> 5, c1 = e1 & 31;
    for (int k0 = 0; k0 < kend; k0 += 32) {
        g2l16(Ab + (long)r0 * lda + k0 + c0, (char*)As + (wid * 2 + 0) * 1024);
        g2l16(Ab + (long)r1 * lda + k0 + c1, (char*)As + (wid * 2 + 1) * 1024);
        g2l16(Bb + (long)r0 * ldb + k0 + c0, (char*)Bs + (wid * 2 + 0) * 1024);
        g2l16(Bb + (long)r1 * ldb + k0 + c1, (char*)Bs + (wid * 2 + 1) * 1024);
        __syncthreads();
        v8bf af[4], bfr[4];
        #pragma unroll
        for (int r = 0; r < 4; ++r)
            af[r] = *(const v8bf*)&As[wm + r * 16 + ln16][q * 8];
        #pragma unroll
        for (int c = 0; c < 4; ++c)
            bfr[c] = *(const v8bf*)&Bs[wn + c * 16 + ln16][q * 8];
        #pragma unroll
        for (int r = 0; r < 4; ++r)
            #pragma unroll
            for (int c = 0; c < 4; ++c)
                acc[r][c] = __builtin_amdgcn_mfma_f32_16x16x32_bf16(
                    af[r], bfr[c], acc[r][c], 0, 0, 0);
        __syncthreads();
    }
    float* Cf = (float*)Cv;
    unsigned short* Cb = (unsigned short*)Cv;
    long zoff = (long)z * sC;
    #pragma unroll
    for (int r = 0; r < 4; ++r) {
        #pragma unroll
        for (int c = 0; c < 4; ++c) {
            #pragma unroll
            for (int e = 0; e < 4; ++e) {
                int row = m0 + wm + r * 16 + q * 4 + e;
                int col = n0 + wn + c * 16 + ln16;
                float v = acc[r][c][e];
                if (RELU) v = fmaxf(v, 0.f);
                if (MASK && row <= col) v = 0.f;
                long idx = zoff + (long)row * ldc + col;
                if (MUL) v *= b2f(mulp[idx]);
                if (BF16OUT) Cb[idx] = f2b(v);
                else         Cf[idx] = v;
            }
        }
    }
}

// ---------------------------------------------------------------------------
// Transpose + cast fp32 -> bf16: out[Cc][R] = (bf16) in[R][Cc], batched.
__global__ __launch_bounds__(256) void trans_cast(
    const float* __restrict__ in, long sIn, unsigned short* __restrict__ out,
    long sOut, int R, int Cc) {
    __shared__ float tl[32][33];
    int z = blockIdx.z;
    int r0 = blockIdx.y * 32, c0 = blockIdx.x * 32;
    int tx = threadIdx.x & 31, ty = threadIdx.x >> 5;
    const float* ip = in + (long)z * sIn;
    unsigned short* op = out + (long)z * sOut;
    #pragma unroll
    for (int j = 0; j < 4; ++j)
        tl[ty + j * 8][tx] = ip[(long)(r0 + ty + j * 8) * Cc + c0 + tx];
    __syncthreads();
    #pragma unroll
    for (int j = 0; j < 4; ++j)
        op[(long)(c0 + ty + j * 8) * R + r0 + tx] = f2b(tl[tx][ty + j * 8]);
}

// fp32 -> bf16 elementwise (n multiple of 1024)
__global__ __launch_bounds__(256) void cast_b(const float* __restrict__ in,
                                              unsigned short* __restrict__ out) {
    long i = ((long)blockIdx.x * 256 + threadIdx.x) * 4;
    float4 v = *(const float4*)&in[i];
    ushort4 o;
    o.x = f2b(v.x); o.y = f2b(v.y); o.z = f2b(v.z); o.w = f2b(v.w);
    *(ushort4*)&out[i] = o;
}

// out = a + b + bias (rows of 512, fp32), n = BT*512
__global__ __launch_bounds__(256) void add_out(const float* __restrict__ a,
                                               const float* __restrict__ b,
                                               const float* __restrict__ bias,
                                               float* __restrict__ o) {
    long i = ((long)blockIdx.x * 256 + threadIdx.x) * 4;
    float4 va = *(const float4*)&a[i];
    float4 vb = *(const float4*)&b[i];
    float4 bv = *(const float4*)&bias[i & 511];
    float4 r;
    r.x = va.x + vb.x + bv.x; r.y = va.y + vb.y + bv.y;
    r.z = va.z + vb.z + bv.z; r.w = va.w + vb.w + bv.w;
    *(float4*)&o[i] = r;
}

// ---------------------------------------------------------------------------
// RoPE: xsp [BT][HN] bf16 -> qr [B][NH][T][NL] bf16 (head-outer layout).
// 4 pairs (16B) per thread.  freq = 2^(-n2/8) / (2*pi), n2 = pair idx in head.
__global__ __launch_bounds__(256) void rope_b(const unsigned short* __restrict__ xsp,
                                              unsigned short* __restrict__ qr) {
    long i = (long)blockIdx.x * 256 + threadIdx.x;  // group of 4 pairs
    int g = (int)(i & 255);                         // HN/8 groups per row
    long row = i >> 8;
    int h = g >> 5, n8 = g & 31;
    long b = row >> 11;
    int t = (int)(row & (T_ - 1));
    us8 u = *(const us8*)&xsp[row * HN_ + (long)g * 8];
    us8 o;
    #pragma unroll
    for (int p = 0; p < 4; ++p) {
        int n2 = n8 * 4 + p;
        float f = exp2f(-(float)n2 * 0.125f) * (float)(1.0 / (2.0 * M_PI));
        float ph = (float)t * f;
        ph = (ph - floorf(ph)) * (float)(2.0 * M_PI);
        float s, c;
        __sincosf(ph, &s, &c);
        float x0 = b2f(u[2 * p]), x1 = b2f(u[2 * p + 1]);
        o[2 * p]     = f2b(x0 * c - x1 * s);
        o[2 * p + 1] = f2b(x1 * c + x0 * s);
    }
    long ob = (((b * NH_ + h) * T_ + t) * NL_) + (long)n8 * 8;
    *(us8*)&qr[ob] = o;
}

// ---------------------------------------------------------------------------
// LayerNorm helpers (rows of 512, 256 threads, float2 per thread)
__device__ inline float2 block_reduce2(float a, float b) {
    __shared__ float sa[4], sb[4];
    #pragma unroll
    for (int off = 32; off; off >>= 1) {
        a += __shfl_down(a, off, 64);
        b += __shfl_down(b, off, 64);
    }
    __syncthreads();
    int w = threadIdx.x >> 6;
    if ((threadIdx.x & 63) == 0) { sa[w] = a; sb[w] = b; }
    __syncthreads();
    return make_float2(sa[0] + sa[1] + sa[2] + sa[3],
                       sb[0] + sb[1] + sb[2] + sb[3]);
}
__device__ inline float2 ln_pair(float2 v) {
    float2 s = block_reduce2(v.x + v.y, 0.f);
    float mu = s.x * (1.0f / 512.0f);
    float dx = v.x - mu, dy = v.y - mu;
    float2 q = block_reduce2(dx * dx + dy * dy, 0.f);
    float inv = rsqrtf(q.x * (1.0f / 512.0f) + 1e-5f);
    return make_float2(dx * inv, dy * inv);
}

// LN(a + b + bias) -> fp32 + bf16
__global__ __launch_bounds__(256) void ln_dual2(const float* __restrict__ a,
                                                const float* __restrict__ b,
                                                const float* __restrict__ bias,
                                                float* __restrict__ outf,
                                                unsigned short* __restrict__ outb) {
    long row = blockIdx.x;
    int c = threadIdx.x * 2;
    float2 va = *(const float2*)&a[row * 512 + c];
    float2 vb = *(const float2*)&b[row * 512 + c];
    float2 bv = *(const float2*)&bias[c];
    float2 v = make_float2(va.x + vb.x + bv.x, va.y + vb.y + bv.y);
    float2 o = ln_pair(v);
    *(float2*)&outf[row * 512 + c] = o;
    ushort2 ob; ob.x = f2b(o.x); ob.y = f2b(o.y);
    *(ushort2*)&outb[row * 512 + c] = ob;
}

// LN bf16 in-place
__global__ __launch_bounds__(256) void ln_b16(unsigned short* __restrict__ buf) {
    long row = blockIdx.x;
    ushort2 u = *(const ushort2*)&buf[row * 512 + threadIdx.x * 2];
    float2 v = make_float2(b2f(u.x), b2f(u.y));
    float2 o = ln_pair(v);
    ushort2 ob; ob.x = f2b(o.x); ob.y = f2b(o.y);
    *(ushort2*)&buf[row * 512 + threadIdx.x * 2] = ob;
}

// xs_next = LN(x_res + LN(ymlpA + ymlpB)) -> fp32 + bf16
__global__ __launch_bounds__(256) void combine_dual2(
    const float* __restrict__ ya, const float* __restrict__ yb,
    const float* __restrict__ xres, float* __restrict__ outf,
    unsigned short* __restrict__ outb) {
    long row = blockIdx.x;
    int c = threadIdx.x * 2;
    float2 a = *(const float2*)&ya[row * 512 + c];
    float2 b = *(const float2*)&yb[row * 512 + c];
    float2 y = make_float2(a.x + b.x, a.y + b.y);
    float2 l = ln_pair(y);
    float2 r = *(const float2*)&xres[row * 512 + c];
    float2 z = make_float2(r.x + l.x, r.y + l.y);
    float2 o = ln_pair(z);
    *(float2*)&outf[row * 512 + c] = o;
    ushort2 ob; ob.x = f2b(o.x); ob.y = f2b(o.y);
    *(ushort2*)&outb[row * 512 + c] = ob;
}

// ---------------------------------------------------------------------------
extern "C" void kernel_launch(void* const* d_in, const int* in_sizes, int n_in,
                              void* d_out, int out_size, void* d_ws,
                              size_t ws_size, hipStream_t stream) {
    const float* x      = (const float*)d_in[0];
    const float* w_in   = (const float*)d_in[1];
    const float* b_in   = (const float*)d_in[2];
    const float* enc    = (const float*)d_in[3];
    const float* enc_v  = (const float*)d_in[4];
    const float* dec    = (const float*)d_in[5];
    const float* head_w = (const float*)d_in[6];
    const float* head_b = (const float*)d_in[7];
    float* out = (float*)d_out;

    // ---- workspace (~209 MB) ----
    char* w = (char*)d_ws;
    auto alloc = [&](size_t bytes) { void* p = (void*)w; w += bytes; return p; };
    unsigned short* w_inT = (unsigned short*)alloc((size_t)512 * 512 * 2);
    unsigned short* headT = (unsigned short*)alloc((size_t)512 * 512 * 2);
    unsigned short* encT  = (unsigned short*)alloc((size_t)NH_ * NL_ * D_ * 2);
    unsigned short* encvT = (unsigned short*)alloc((size_t)NH_ * NL_ * D_ * 2);
    unsigned short* decT  = (unsigned short*)alloc((size_t)D_ * HN_ * 2);
    unsigned short* xb    = (unsigned short*)alloc((size_t)BT_ * D_ * 2);
    float*          tmp   = (float*)alloc((size_t)2 * BT_ * D_ * 4);  // 2 K-halves
    float*          xsf0  = (float*)alloc((size_t)BT_ * D_ * 4);
    float*          xsf1  = (float*)alloc((size_t)BT_ * D_ * 4);
    unsigned short* xs_b  = (unsigned short*)alloc((size_t)BT_ * D_ * 2);
    unsigned short* xsT   = (unsigned short*)alloc((size_t)B_ * D_ * T_ * 2);
    unsigned short* xsp   = (unsigned short*)alloc((size_t)BT_ * HN_ * 2);
    unsigned short* qrh   = (unsigned short*)alloc((size_t)BT_ * HN_ * 2);  // [B][NH][T][NL]
    unsigned short* Sm    = (unsigned short*)alloc((size_t)NH_ * T_ * T_ * 2);
    unsigned short* ykv   = (unsigned short*)alloc((size_t)NH_ * BT_ * D_ * 2);
    float* tmp2 = tmp + (size_t)BT_ * D_;

    // ---- prep ----
    cast_b<<<BT_ * D_ / 1024, 256, 0, stream>>>(x, xb);
    trans_cast<<<dim3(16, 16, 1), 256, 0, stream>>>(w_in, 0, w_inT, 0, 512, 512);
    trans_cast<<<dim3(16, 16, 1), 256, 0, stream>>>(head_w, 0, headT, 0, 512, 512);
    trans_cast<<<dim3(8, 16, 8), 256, 0, stream>>>(enc, (long)D_ * NL_, encT,
                                                   (long)NL_ * D_, D_, NL_);
    trans_cast<<<dim3(8, 16, 8), 256, 0, stream>>>(enc_v, (long)D_ * NL_, encvT,
                                                   (long)NL_ * D_, D_, NL_);
    trans_cast<<<dim3(16, 64, 1), 256, 0, stream>>>(dec, 0, decT, 0, HN_, D_);

    // ---- xs = LN(x @ w_in + b_in)  (split-K=2) ----
    gemm_bf16<false, false, false, false, false>
        <<<dim3(4, 32, 2), 256, 0, stream>>>(xb, D_, 256, w_inT, D_, 256, tmp,
                                             D_, (long)BT_ * D_, nullptr, BT_,
                                             D_, 256);
    ln_dual2<<<BT_, 256, 0, stream>>>(tmp, tmp2, b_in, xsf0, xs_b);
    trans_cast<<<dim3(16, 64, 2), 256, 0, stream>>>(xsf0, (long)T_ * D_, xsT,
                                                    (long)D_ * T_, T_, D_);

    float* xin = xsf0;
    float* xout = xsf1;
    for (int l = 0; l < 3; ++l) {
        // x_sparse = relu(xs @ enc[h]) -> bf16 [BT][HN]
        gemm_bf16<true, false, false, false, true>
            <<<dim3(2, 32, 8), 256, 0, stream>>>(
                xs_b, D_, 0, encT, D_, (long)NL_ * D_, xsp, HN_, NL_, nullptr,
                BT_, NL_, D_);
        // QR = rope(x_sparse) -> [B][NH][T][NL]
        rope_b<<<BT_ * HN_ / 8 / 256, 256, 0, stream>>>(xsp, qrh);
        for (int b = 0; b < B_; ++b) {
            const unsigned short* qb = qrh + (long)b * NH_ * T_ * NL_;
            // S = strict_tril(QR QR^T)
            gemm_bf16<false, false, true, false, true>
                <<<dim3(16, 16, 8), 256, 0, stream>>>(
                    qb, NL_, (long)T_ * NL_, qb, NL_, (long)T_ * NL_, Sm, T_,
                    (long)T_ * T_, nullptr, T_, T_, NL_);
            // yKV = S @ xs  (K causally bounded) -> bf16 [h][b*T..][D]
            gemm_bf16<false, false, false, true, true>
                <<<dim3(4, 16, 8), 256, 0, stream>>>(
                    Sm, T_, (long)T_ * T_, xsT + (long)b * D_ * T_, T_, 0,
                    ykv + (long)b * T_ * D_, D_, (long)BT_ * D_, nullptr, T_,
                    D_, T_);
        }
        // yKV = LN(yKV) in place
        ln_b16<<<NH_ * BT_, 256, 0, stream>>>(ykv);
        // xy = relu(yKV @ enc_v[h]) * x_sparse  (in place into xsp)
        gemm_bf16<true, true, false, false, true>
            <<<dim3(2, 32, 8), 256, 0, stream>>>(
                ykv, D_, (long)BT_ * D_, encvT, D_, (long)NL_ * D_, xsp, HN_,
                NL_, xsp, BT_, NL_, D_);
        // yMLP = xy @ decoder  (split-K=2) -> fp32 halves
        gemm_bf16<false, false, false, false, false>
            <<<dim3(4, 32, 2), 256, 0, stream>>>(
                xsp, HN_, 1024, decT, HN_, 1024, tmp, D_, (long)BT_ * D_,
                nullptr, BT_, D_, 1024);
        // xs = LN(x_res + LN(yMLP))
        combine_dual2<<<BT_, 256, 0, stream>>>(tmp, tmp2, xin, xout, xs_b);
        trans_cast<<<dim3(16, 64, 2), 256, 0, stream>>>(xout, (long)T_ * D_,
                                                        xsT, (long)D_ * T_, T_,
                                                        D_);
        float* t = xin; xin = xout; xout = t;
    }

    // logits = xs @ head_w + head_b  (split-K=2)
    gemm_bf16<false, false, false, false, false>
        <<<dim3(4, 32, 2), 256, 0, stream>>>(xs_b, D_, 256, headT, D_, 256, tmp,
                                             D_, (long)BT_ * D_, nullptr, BT_,
                                             D_, 256);
    add_out<<<BT_ * 512 / 1024, 256, 0, stream>>>(tmp, tmp2, head_b, out);
}

// Round 4
// 830.347 us; speedup vs baseline: 30.3367x; 1.1716x over previous
//
#include <hip/hip_runtime.h>
#include <math.h>

constexpr int B_  = 2;
constexpr int T_  = 2048;
constexpr int D_  = 512;
constexpr int NH_ = 8;
constexpr int NL_ = 256;
constexpr int HN_ = NH_ * NL_;   // 2048
constexpr int BT_ = B_ * T_;     // 4096
constexpr int NTIL = 16;         // T/128
constexpr int NTRI = NTIL * (NTIL + 1) / 2;      // 136 lower tiles
constexpr long STILE = (long)NTRI * 128 * 128;   // elems per (b,h) S slice

typedef __bf16 v8bf __attribute__((ext_vector_type(8)));
typedef float  v4f  __attribute__((ext_vector_type(4)));
typedef unsigned short us8 __attribute__((ext_vector_type(8)));

__device__ inline unsigned short f2b(float f) {
    union { float f; unsigned u; } v{f};
    unsigned r = v.u + 0x7FFF + ((v.u >> 16) & 1);   // rtne
    return (unsigned short)(r >> 16);
}
__device__ inline float b2f(unsigned short u) {
    union { unsigned u; float f; } v{(unsigned)u << 16};
    return v.f;
}

// async 16B global->LDS (per-lane gaddr; LDS dest = wave-uniform base + lane*16)
__device__ __forceinline__ void g2l16(const void* g, void* l) {
    __builtin_amdgcn_global_load_lds(
        (const __attribute__((address_space(1))) void*)g,
        (__attribute__((address_space(3))) void*)l, 16, 0, 0);
}

// Shared MFMA tile core helpers (128x128 tile, BK=32, 4 waves, 4x4 MFMA/wave)
#define TILE_IDS                                              \
    int tid = threadIdx.x;                                    \
    int lane = tid & 63, wid = tid >> 6;                      \
    int wm = (wid & 1) * 64, wn = (wid >> 1) * 64;            \
    int ln16 = lane & 15, q = lane >> 4;                      \
    int e0 = (wid * 2 + 0) * 512 + lane * 8;                  \
    int e1 = (wid * 2 + 1) * 512 + lane * 8;                  \
    int r0 = e0 >> 5, c0 = e0 & 31, r1 = e1 >> 5, c1 = e1 & 31;

#define TILE_MFMA(As, Bs)                                     \
    {                                                         \
        v8bf af[4], bfr[4];                                   \
        _Pragma("unroll")                                     \
        for (int r = 0; r < 4; ++r)                           \
            af[r] = *(const v8bf*)&As[wm + r * 16 + ln16][q * 8]; \
        _Pragma("unroll")                                     \
        for (int c = 0; c < 4; ++c)                           \
            bfr[c] = *(const v8bf*)&Bs[wn + c * 16 + ln16][q * 8]; \
        _Pragma("unroll")                                     \
        for (int r = 0; r < 4; ++r)                           \
            _Pragma("unroll")                                 \
            for (int c = 0; c < 4; ++c)                       \
                acc[r][c] = __builtin_amdgcn_mfma_f32_16x16x32_bf16( \
                    af[r], bfr[c], acc[r][c], 0, 0, 0);       \
    }

// ---------------------------------------------------------------------------
// Generic bf16 MFMA GEMM: C[M,N] = A[M,K] @ Bt[N,K]^T (Bt K-major), z-batched.
template <bool RELU, bool MUL, bool BF16OUT>
__global__ __launch_bounds__(256) void gemm_bf16(
    const unsigned short* __restrict__ A, int lda, long sA,
    const unsigned short* __restrict__ Bt, int ldb, long sB,
    void* __restrict__ Cv, int ldc, long sC,
    const unsigned short* __restrict__ mulp, int M, int N, int K) {
    int m0 = blockIdx.y * 128, n0 = blockIdx.x * 128, z = blockIdx.z;
    __shared__ unsigned short As[128][32];
    __shared__ unsigned short Bs[128][32];
    const unsigned short* Ab = A  + (long)z * sA + (long)m0 * lda;
    const unsigned short* Bb = Bt + (long)z * sB + (long)n0 * ldb;
    TILE_IDS
    v4f acc[4][4] = {};
    for (int k0 = 0; k0 < K; k0 += 32) {
        g2l16(Ab + (long)r0 * lda + k0 + c0, (char*)As + (wid * 2 + 0) * 1024);
        g2l16(Ab + (long)r1 * lda + k0 + c1, (char*)As + (wid * 2 + 1) * 1024);
        g2l16(Bb + (long)r0 * ldb + k0 + c0, (char*)Bs + (wid * 2 + 0) * 1024);
        g2l16(Bb + (long)r1 * ldb + k0 + c1, (char*)Bs + (wid * 2 + 1) * 1024);
        __syncthreads();
        TILE_MFMA(As, Bs)
        __syncthreads();
    }
    float* Cf = (float*)Cv;
    unsigned short* Cb = (unsigned short*)Cv;
    long zoff = (long)z * sC;
    #pragma unroll
    for (int r = 0; r < 4; ++r)
        #pragma unroll
        for (int c = 0; c < 4; ++c)
            #pragma unroll
            for (int e = 0; e < 4; ++e) {
                int row = m0 + wm + r * 16 + q * 4 + e;
                int col = n0 + wn + c * 16 + ln16;
                float v = acc[r][c][e];
                if (RELU) v = fmaxf(v, 0.f);
                long idx = zoff + (long)row * ldc + col;
                if (MUL) v *= b2f(mulp[idx]);
                if (BF16OUT) Cb[idx] = f2b(v);
                else         Cf[idx] = v;
            }
}

// ---------------------------------------------------------------------------
// S-GEMM: packed-triangular scores.  grid (NTRI, 1, 16); z = b*8+h.
// Tile x -> (i,j), i>=j.  S_tile = QR[i-tile] @ QR[j-tile]^T, strict mask on
// diagonal tiles.  Output: Sp[z][x][128][128] bf16.
__global__ __launch_bounds__(256) void s_gemm(const unsigned short* __restrict__ qr,
                                              unsigned short* __restrict__ Sp) {
    int x = blockIdx.x, z = blockIdx.z;
    int i = 0, rem = x;
    while (rem >= i + 1) { rem -= i + 1; ++i; }
    int j = rem;                       // tile (i, j), j <= i
    const unsigned short* zb = qr + (long)z * T_ * NL_;
    const unsigned short* Ab = zb + (long)(i * 128) * NL_;
    const unsigned short* Bb = zb + (long)(j * 128) * NL_;
    __shared__ unsigned short As[128][32];
    __shared__ unsigned short Bs[128][32];
    TILE_IDS
    v4f acc[4][4] = {};
    for (int k0 = 0; k0 < NL_; k0 += 32) {
        g2l16(Ab + (long)r0 * NL_ + k0 + c0, (char*)As + (wid * 2 + 0) * 1024);
        g2l16(Ab + (long)r1 * NL_ + k0 + c1, (char*)As + (wid * 2 + 1) * 1024);
        g2l16(Bb + (long)r0 * NL_ + k0 + c0, (char*)Bs + (wid * 2 + 0) * 1024);
        g2l16(Bb + (long)r1 * NL_ + k0 + c1, (char*)Bs + (wid * 2 + 1) * 1024);
        __syncthreads();
        TILE_MFMA(As, Bs)
        __syncthreads();
    }
    unsigned short* ob = Sp + (long)z * STILE + (long)x * 16384;
    bool diag = (i == j);
    #pragma unroll
    for (int r = 0; r < 4; ++r)
        #pragma unroll
        for (int c = 0; c < 4; ++c)
            #pragma unroll
            for (int e = 0; e < 4; ++e) {
                int row = wm + r * 16 + q * 4 + e;
                int col = wn + c * 16 + ln16;
                float v = acc[r][c][e];
                if (diag && row <= col) v = 0.f;   // strict causal
                ob[row * 128 + col] = f2b(v);
            }
}

// ---------------------------------------------------------------------------
// PX-GEMM: yKV = S @ xs with packed-tri A.  grid (4, 16, 16); z = b*8+h.
// my = 15 - blockIdx.y (heavy blocks dispatch first).  K runs 0..(my+1)*128.
// B = xsT [b][D][T] (K-major).  Out: ykv [h][b*T + t][D] bf16.
__global__ __launch_bounds__(256) void px_gemm(const unsigned short* __restrict__ Sp,
                                               const unsigned short* __restrict__ xsT,
                                               unsigned short* __restrict__ ykv) {
    int my = (NTIL - 1) - blockIdx.y;
    int n0 = blockIdx.x * 128, z = blockIdx.z;
    int b = z >> 3, h = z & 7;
    const unsigned short* Ab =
        Sp + (long)z * STILE + (long)(my * (my + 1) / 2) * 16384;
    const unsigned short* Bb = xsT + (long)b * D_ * T_ + (long)n0 * T_;
    __shared__ unsigned short As[128][32];
    __shared__ unsigned short Bs[128][32];
    TILE_IDS
    v4f acc[4][4] = {};
    int kend = (my + 1) * 128;
    for (int k0 = 0; k0 < kend; k0 += 32) {
        const unsigned short* At = Ab + ((long)(k0 >> 7) << 14) + (k0 & 127);
        g2l16(At + r0 * 128 + c0, (char*)As + (wid * 2 + 0) * 1024);
        g2l16(At + r1 * 128 + c1, (char*)As + (wid * 2 + 1) * 1024);
        g2l16(Bb + (long)r0 * T_ + k0 + c0, (char*)Bs + (wid * 2 + 0) * 1024);
        g2l16(Bb + (long)r1 * T_ + k0 + c1, (char*)Bs + (wid * 2 + 1) * 1024);
        __syncthreads();
        TILE_MFMA(As, Bs)
        __syncthreads();
    }
    #pragma unroll
    for (int r = 0; r < 4; ++r)
        #pragma unroll
        for (int c = 0; c < 4; ++c)
            #pragma unroll
            for (int e = 0; e < 4; ++e) {
                int t = my * 128 + wm + r * 16 + q * 4 + e;
                int d = n0 + wn + c * 16 + ln16;
                long orow = (long)h * BT_ + (long)b * T_ + t;
                ykv[orow * D_ + d] = f2b(acc[r][c][e]);
            }
}

// ---------------------------------------------------------------------------
// Transpose + cast fp32 -> bf16: out[Cc][R] = (bf16) in[R][Cc], batched.
__global__ __launch_bounds__(256) void trans_cast(
    const float* __restrict__ in, long sIn, unsigned short* __restrict__ out,
    long sOut, int R, int Cc) {
    __shared__ float tl[32][33];
    int z = blockIdx.z;
    int r0 = blockIdx.y * 32, c0 = blockIdx.x * 32;
    int tx = threadIdx.x & 31, ty = threadIdx.x >> 5;
    const float* ip = in + (long)z * sIn;
    unsigned short* op = out + (long)z * sOut;
    #pragma unroll
    for (int j = 0; j < 4; ++j)
        tl[ty + j * 8][tx] = ip[(long)(r0 + ty + j * 8) * Cc + c0 + tx];
    __syncthreads();
    #pragma unroll
    for (int j = 0; j < 4; ++j)
        op[(long)(c0 + ty + j * 8) * R + r0 + tx] = f2b(tl[tx][ty + j * 8]);
}

// fp32 -> bf16 elementwise (n multiple of 1024)
__global__ __launch_bounds__(256) void cast_b(const float* __restrict__ in,
                                              unsigned short* __restrict__ out) {
    long i = ((long)blockIdx.x * 256 + threadIdx.x) * 4;
    float4 v = *(const float4*)&in[i];
    ushort4 o;
    o.x = f2b(v.x); o.y = f2b(v.y); o.z = f2b(v.z); o.w = f2b(v.w);
    *(ushort4*)&out[i] = o;
}

// out = a + b + bias (rows of 512, fp32)
__global__ __launch_bounds__(256) void add_out(const float* __restrict__ a,
                                               const float* __restrict__ b,
                                               const float* __restrict__ bias,
                                               float* __restrict__ o) {
    long i = ((long)blockIdx.x * 256 + threadIdx.x) * 4;
    float4 va = *(const float4*)&a[i];
    float4 vb = *(const float4*)&b[i];
    float4 bv = *(const float4*)&bias[i & 511];
    float4 r;
    r.x = va.x + vb.x + bv.x; r.y = va.y + vb.y + bv.y;
    r.z = va.z + vb.z + bv.z; r.w = va.w + vb.w + bv.w;
    *(float4*)&o[i] = r;
}

// ---------------------------------------------------------------------------
// RoPE: xsp [BT][HN] bf16 -> qr [B][NH][T][NL] bf16 (head-outer layout).
__global__ __launch_bounds__(256) void rope_b(const unsigned short* __restrict__ xsp,
                                              unsigned short* __restrict__ qr) {
    long i = (long)blockIdx.x * 256 + threadIdx.x;  // group of 4 pairs
    int g = (int)(i & 255);
    long row = i >> 8;
    int h = g >> 5, n8 = g & 31;
    long b = row >> 11;
    int t = (int)(row & (T_ - 1));
    us8 u = *(const us8*)&xsp[row * HN_ + (long)g * 8];
    us8 o;
    #pragma unroll
    for (int p = 0; p < 4; ++p) {
        int n2 = n8 * 4 + p;
        float f = exp2f(-(float)n2 * 0.125f) * (float)(1.0 / (2.0 * M_PI));
        float ph = (float)t * f;
        ph = (ph - floorf(ph)) * (float)(2.0 * M_PI);
        float s, c;
        __sincosf(ph, &s, &c);
        float x0 = b2f(u[2 * p]), x1 = b2f(u[2 * p + 1]);
        o[2 * p]     = f2b(x0 * c - x1 * s);
        o[2 * p + 1] = f2b(x1 * c + x0 * s);
    }
    long ob = (((b * NH_ + h) * T_ + t) * NL_) + (long)n8 * 8;
    *(us8*)&qr[ob] = o;
}

// ---------------------------------------------------------------------------
// LayerNorm helpers (rows of 512, 256 threads, float2 per thread)
__device__ inline float2 block_reduce2(float a, float b) {
    __shared__ float sa[4], sb[4];
    #pragma unroll
    for (int off = 32; off; off >>= 1) {
        a += __shfl_down(a, off, 64);
        b += __shfl_down(b, off, 64);
    }
    __syncthreads();
    int w = threadIdx.x >> 6;
    if ((threadIdx.x & 63) == 0) { sa[w] = a; sb[w] = b; }
    __syncthreads();
    return make_float2(sa[0] + sa[1] + sa[2] + sa[3],
                       sb[0] + sb[1] + sb[2] + sb[3]);
}
__device__ inline float2 ln_pair(float2 v) {
    float2 s = block_reduce2(v.x + v.y, 0.f);
    float mu = s.x * (1.0f / 512.0f);
    float dx = v.x - mu, dy = v.y - mu;
    float2 q = block_reduce2(dx * dx + dy * dy, 0.f);
    float inv = rsqrtf(q.x * (1.0f / 512.0f) + 1e-5f);
    return make_float2(dx * inv, dy * inv);
}

// LN(a + b + bias) -> fp32 + bf16
__global__ __launch_bounds__(256) void ln_dual2(const float* __restrict__ a,
                                                const float* __restrict__ b,
                                                const float* __restrict__ bias,
                                                float* __restrict__ outf,
                                                unsigned short* __restrict__ outb) {
    long row = blockIdx.x;
    int c = threadIdx.x * 2;
    float2 va = *(const float2*)&a[row * 512 + c];
    float2 vb = *(const float2*)&b[row * 512 + c];
    float2 bv = *(const float2*)&bias[c];
    float2 v = make_float2(va.x + vb.x + bv.x, va.y + vb.y + bv.y);
    float2 o = ln_pair(v);
    *(float2*)&outf[row * 512 + c] = o;
    ushort2 ob; ob.x = f2b(o.x); ob.y = f2b(o.y);
    *(ushort2*)&outb[row * 512 + c] = ob;
}

// LN bf16 in-place
__global__ __launch_bounds__(256) void ln_b16(unsigned short* __restrict__ buf) {
    long row = blockIdx.x;
    ushort2 u = *(const ushort2*)&buf[row * 512 + threadIdx.x * 2];
    float2 v = make_float2(b2f(u.x), b2f(u.y));
    float2 o = ln_pair(v);
    ushort2 ob; ob.x = f2b(o.x); ob.y = f2b(o.y);
    *(ushort2*)&buf[row * 512 + threadIdx.x * 2] = ob;
}

// xs_next = LN(x_res + LN(ymlpA + ymlpB)) -> fp32 + bf16
__global__ __launch_bounds__(256) void combine_dual2(
    const float* __restrict__ ya, const float* __restrict__ yb,
    const float* __restrict__ xres, float* __restrict__ outf,
    unsigned short* __restrict__ outb) {
    long row = blockIdx.x;
    int c = threadIdx.x * 2;
    float2 a = *(const float2*)&ya[row * 512 + c];
    float2 b = *(const float2*)&yb[row * 512 + c];
    float2 y = make_float2(a.x + b.x, a.y + b.y);
    float2 l = ln_pair(y);
    float2 r = *(const float2*)&xres[row * 512 + c];
    float2 z = make_float2(r.x + l.x, r.y + l.y);
    float2 o = ln_pair(z);
    *(float2*)&outf[row * 512 + c] = o;
    ushort2 ob; ob.x = f2b(o.x); ob.y = f2b(o.y);
    *(ushort2*)&outb[row * 512 + c] = ob;
}

// ---------------------------------------------------------------------------
extern "C" void kernel_launch(void* const* d_in, const int* in_sizes, int n_in,
                              void* d_out, int out_size, void* d_ws,
                              size_t ws_size, hipStream_t stream) {
    const float* x      = (const float*)d_in[0];
    const float* w_in   = (const float*)d_in[1];
    const float* b_in   = (const float*)d_in[2];
    const float* enc    = (const float*)d_in[3];
    const float* enc_v  = (const float*)d_in[4];
    const float* dec    = (const float*)d_in[5];
    const float* head_w = (const float*)d_in[6];
    const float* head_b = (const float*)d_in[7];
    float* out = (float*)d_out;

    // ---- workspace (~211 MB) ----
    char* w = (char*)d_ws;
    auto alloc = [&](size_t bytes) { void* p = (void*)w; w += bytes; return p; };
    unsigned short* w_inT = (unsigned short*)alloc((size_t)512 * 512 * 2);
    unsigned short* headT = (unsigned short*)alloc((size_t)512 * 512 * 2);
    unsigned short* encT  = (unsigned short*)alloc((size_t)NH_ * NL_ * D_ * 2);
    unsigned short* encvT = (unsigned short*)alloc((size_t)NH_ * NL_ * D_ * 2);
    unsigned short* decT  = (unsigned short*)alloc((size_t)D_ * HN_ * 2);
    unsigned short* xb    = (unsigned short*)alloc((size_t)BT_ * D_ * 2);
    float*          tmp   = (float*)alloc((size_t)2 * BT_ * D_ * 4);  // 2 K-halves
    float*          xsf0  = (float*)alloc((size_t)BT_ * D_ * 4);
    float*          xsf1  = (float*)alloc((size_t)BT_ * D_ * 4);
    unsigned short* xs_b  = (unsigned short*)alloc((size_t)BT_ * D_ * 2);
    unsigned short* xsT   = (unsigned short*)alloc((size_t)B_ * D_ * T_ * 2);
    unsigned short* xsp   = (unsigned short*)alloc((size_t)BT_ * HN_ * 2);
    unsigned short* qrh   = (unsigned short*)alloc((size_t)BT_ * HN_ * 2);  // [B][NH][T][NL]
    unsigned short* Sp    = (unsigned short*)alloc((size_t)16 * STILE * 2); // packed tri
    unsigned short* ykv   = (unsigned short*)alloc((size_t)NH_ * BT_ * D_ * 2);
    float* tmp2 = tmp + (size_t)BT_ * D_;

    // ---- prep ----
    cast_b<<<BT_ * D_ / 1024, 256, 0, stream>>>(x, xb);
    trans_cast<<<dim3(16, 16, 1), 256, 0, stream>>>(w_in, 0, w_inT, 0, 512, 512);
    trans_cast<<<dim3(16, 16, 1), 256, 0, stream>>>(head_w, 0, headT, 0, 512, 512);
    trans_cast<<<dim3(8, 16, 8), 256, 0, stream>>>(enc, (long)D_ * NL_, encT,
                                                   (long)NL_ * D_, D_, NL_);
    trans_cast<<<dim3(8, 16, 8), 256, 0, stream>>>(enc_v, (long)D_ * NL_, encvT,
                                                   (long)NL_ * D_, D_, NL_);
    trans_cast<<<dim3(16, 64, 1), 256, 0, stream>>>(dec, 0, decT, 0, HN_, D_);

    // ---- xs = LN(x @ w_in + b_in)  (split-K=2) ----
    gemm_bf16<false, false, false>
        <<<dim3(4, 32, 2), 256, 0, stream>>>(xb, D_, 256, w_inT, D_, 256, tmp,
                                             D_, (long)BT_ * D_, nullptr, BT_,
                                             D_, 256);
    ln_dual2<<<BT_, 256, 0, stream>>>(tmp, tmp2, b_in, xsf0, xs_b);
    trans_cast<<<dim3(16, 64, 2), 256, 0, stream>>>(xsf0, (long)T_ * D_, xsT,
                                                    (long)D_ * T_, T_, D_);

    float* xin = xsf0;
    float* xout = xsf1;
    for (int l = 0; l < 3; ++l) {
        // x_sparse = relu(xs @ enc[h]) -> bf16 [BT][HN]
        gemm_bf16<true, false, true>
            <<<dim3(2, 32, 8), 256, 0, stream>>>(
                xs_b, D_, 0, encT, D_, (long)NL_ * D_, xsp, HN_, NL_, nullptr,
                BT_, NL_, D_);
        // QR = rope(x_sparse) -> [B][NH][T][NL]
        rope_b<<<BT_ * HN_ / 8 / 256, 256, 0, stream>>>(xsp, qrh);
        // S = strict_tril(QR QR^T), packed tiles, all (b,h) in one launch
        s_gemm<<<dim3(NTRI, 1, 16), 256, 0, stream>>>(qrh, Sp);
        // yKV = S @ xs, all (b,h) in one launch, heavy-first
        px_gemm<<<dim3(4, NTIL, 16), 256, 0, stream>>>(Sp, xsT, ykv);
        // yKV = LN(yKV) in place
        ln_b16<<<NH_ * BT_, 256, 0, stream>>>(ykv);
        // xy = relu(yKV @ enc_v[h]) * x_sparse  (in place into xsp)
        gemm_bf16<true, true, true>
            <<<dim3(2, 32, 8), 256, 0, stream>>>(
                ykv, D_, (long)BT_ * D_, encvT, D_, (long)NL_ * D_, xsp, HN_,
                NL_, xsp, BT_, NL_, D_);
        // yMLP = xy @ decoder  (split-K=2) -> fp32 halves
        gemm_bf16<false, false, false>
            <<<dim3(4, 32, 2), 256, 0, stream>>>(
                xsp, HN_, 1024, decT, HN_, 1024, tmp, D_, (long)BT_ * D_,
                nullptr, BT_, D_, 1024);
        // xs = LN(x_res + LN(yMLP))
        combine_dual2<<<BT_, 256, 0, stream>>>(tmp, tmp2, xin, xout, xs_b);
        trans_cast<<<dim3(16, 64, 2), 256, 0, stream>>>(xout, (long)T_ * D_,
                                                        xsT, (long)D_ * T_, T_,
                                                        D_);
        float* t = xin; xin = xout; xout = t;
    }

    // logits = xs @ head_w + head_b  (split-K=2)
    gemm_bf16<false, false, false>
        <<<dim3(4, 32, 2), 256, 0, stream>>>(xs_b, D_, 256, headT, D_, 256, tmp,
                                             D_, (long)BT_ * D_, nullptr, BT_,
                                             D_, 256);
    add_out<<<BT_ * 512 / 1024, 256, 0, stream>>>(tmp, tmp2, head_b, out);
}